// Round 1
// baseline (1023.885 us; speedup 1.0000x reference)
//
#include <hip/hip_runtime.h>
#include <stdint.h>

// Problem constants (B=64, N=197)
#define M_TOK 12608      // 64*197 tokens
#define CIN   768
#define CD    256
#define NE    8192
#define NCHUNK 8         // nE split into 8 chunks of 1024 for the dist kernel
#define CHUNK  1024

typedef unsigned long long u64;
typedef unsigned int u32;

// ---------------------------------------------------------------------------
// Kernel: per-codeword squared norms  enorm[j] = sum_k emb[j][k]^2
// grid 2048 x 256: each 64-lane wave handles one row (256 floats = 4/lane)
__global__ __launch_bounds__(256) void k_enorm(const float* __restrict__ emb,
                                               float* __restrict__ enorm)
{
    int row  = blockIdx.x * 4 + (threadIdx.x >> 6);
    int lane = threadIdx.x & 63;
    float4 v = *(const float4*)&emb[(size_t)row * CD + lane * 4];
    float s = v.x*v.x + v.y*v.y + v.z*v.z + v.w*v.w;
    #pragma unroll
    for (int o = 32; o; o >>= 1) s += __shfl_down(s, o, 64);
    if (lane == 0) enorm[row] = s;
}

// ---------------------------------------------------------------------------
// Kernel: compress GEMM  zc[M,256] = z[M,768] @ Wc[768,256] + bc
// 64x64 tile, BK=16, 256 threads, 4x4 micro-tile
#define BK1 16
__global__ __launch_bounds__(256) void k_compress(const float* __restrict__ z,
                                                  const float* __restrict__ W,
                                                  const float* __restrict__ bias,
                                                  float* __restrict__ zc)
{
    __shared__ __align__(16) float As[BK1][64 + 4];
    __shared__ __align__(16) float Bs[BK1][64 + 4];
    const int t  = threadIdx.x;
    const int tx = t & 15, ty = t >> 4;
    const int row0 = blockIdx.x * 64;   // 197 blocks
    const int col0 = blockIdx.y * 64;   // 4 blocks

    const int la_r = t >> 2;            // 0..63
    const int la_k = (t & 3) << 2;      // 0,4,8,12
    const int lb_k = t >> 4;            // 0..15
    const int lb_n = (t & 15) << 2;     // 0..60

    float acc[4][4] = {};

    for (int k0 = 0; k0 < CIN; k0 += BK1) {
        float4 a4 = *(const float4*)&z[(size_t)(row0 + la_r) * CIN + k0 + la_k];
        float4 b4 = *(const float4*)&W[(size_t)(k0 + lb_k) * CD + col0 + lb_n];
        __syncthreads();
        As[la_k + 0][la_r] = a4.x; As[la_k + 1][la_r] = a4.y;
        As[la_k + 2][la_r] = a4.z; As[la_k + 3][la_r] = a4.w;
        *(float4*)&Bs[lb_k][lb_n] = b4;
        __syncthreads();
        #pragma unroll
        for (int k = 0; k < BK1; ++k) {
            float a[4], b[4];
            *(float4*)&a[0] = *(const float4*)&As[k][ty * 4];
            *(float4*)&b[0] = *(const float4*)&Bs[k][tx * 4];
            #pragma unroll
            for (int i = 0; i < 4; ++i)
                #pragma unroll
                for (int j = 0; j < 4; ++j)
                    acc[i][j] = fmaf(a[i], b[j], acc[i][j]);
        }
    }

    float4 bb = *(const float4*)&bias[col0 + tx * 4];
    #pragma unroll
    for (int i = 0; i < 4; ++i) {
        float4 v;
        v.x = acc[i][0] + bb.x; v.y = acc[i][1] + bb.y;
        v.z = acc[i][2] + bb.z; v.w = acc[i][3] + bb.w;
        *(float4*)&zc[(size_t)(row0 + ty * 4 + i) * CD + col0 + tx * 4] = v;
    }
}

// ---------------------------------------------------------------------------
// Kernel: fused distance GEMM + per-row argmin over a 1024-codeword chunk.
// Block = 128 rows x CHUNK cols (8 tiles of 128), BK=16, 256 threads,
// 8x8 micro split as two 4-wide sub-blocks at +64 (2-way-free LDS reads).
// d'(m,j) = enorm[j] - 2*dot(zc_m, e_j)   (same argmin as full distance)
#define BK2 16
__global__ __launch_bounds__(256) void k_dist(const float* __restrict__ zc,
                                              const float* __restrict__ emb,
                                              const float* __restrict__ enorm,
                                              u64* __restrict__ part)
{
    __shared__ __align__(16) float As[BK2][128 + 4];
    __shared__ __align__(16) float Bs[BK2][128 + 4];
    __shared__ u64 red[128][17];
    __shared__ u64 best[128];

    const int t  = threadIdx.x;
    const int tx = t & 15, ty = t >> 4;
    const int row0  = blockIdx.x * 128;        // 99 blocks (last partially valid)
    const int chunk = blockIdx.y;              // 0..7
    const int jbase = chunk * CHUNK;

    if (t < 128) best[t] = ~0ull;
    __syncthreads();

    for (int tile = 0; tile < CHUNK / 128; ++tile) {
        const int j0 = jbase + tile * 128;
        float acc[8][8] = {};

        for (int k0 = 0; k0 < CD; k0 += BK2) {
            float4 av[2], bv[2];
            #pragma unroll
            for (int i = 0; i < 2; ++i) {
                int t2 = t + 256 * i;
                int r  = t2 >> 2;
                int kc = (t2 & 3) << 2;
                int row = row0 + r; row = row < M_TOK ? row : (M_TOK - 1);
                av[i] = *(const float4*)&zc [(size_t)row * CD + k0 + kc];
                bv[i] = *(const float4*)&emb[(size_t)(j0 + r) * CD + k0 + kc];
            }
            __syncthreads();
            #pragma unroll
            for (int i = 0; i < 2; ++i) {
                int t2 = t + 256 * i;
                int r  = t2 >> 2;
                int kc = (t2 & 3) << 2;
                As[kc + 0][r] = av[i].x; As[kc + 1][r] = av[i].y;
                As[kc + 2][r] = av[i].z; As[kc + 3][r] = av[i].w;
                Bs[kc + 0][r] = bv[i].x; Bs[kc + 1][r] = bv[i].y;
                Bs[kc + 2][r] = bv[i].z; Bs[kc + 3][r] = bv[i].w;
            }
            __syncthreads();
            #pragma unroll
            for (int k = 0; k < BK2; ++k) {
                float a[8], b[8];
                *(float4*)&a[0] = *(const float4*)&As[k][ty * 4];
                *(float4*)&a[4] = *(const float4*)&As[k][64 + ty * 4];
                *(float4*)&b[0] = *(const float4*)&Bs[k][tx * 4];
                *(float4*)&b[4] = *(const float4*)&Bs[k][64 + tx * 4];
                #pragma unroll
                for (int i = 0; i < 8; ++i)
                    #pragma unroll
                    for (int j = 0; j < 8; ++j)
                        acc[i][j] = fmaf(a[i], b[j], acc[i][j]);
            }
        }

        // distances + per-thread argmin over this thread's 8 columns
        float en[8];
        *(float4*)&en[0] = *(const float4*)&enorm[j0 + tx * 4];
        *(float4*)&en[4] = *(const float4*)&enorm[j0 + 64 + tx * 4];
        #pragma unroll
        for (int i = 0; i < 8; ++i) {
            u64 bb = ~0ull;
            #pragma unroll
            for (int j = 0; j < 8; ++j) {
                float d = en[j] - 2.0f * acc[i][j];
                int col = j0 + ((j < 4) ? (tx * 4 + j) : (64 + tx * 4 + (j - 4)));
                u32 u = __float_as_uint(d);
                u = (u & 0x80000000u) ? ~u : (u | 0x80000000u);
                u64 key = ((u64)u << 32) | (u32)col;
                bb = key < bb ? key : bb;
            }
            int rloc = (i < 4) ? (ty * 4 + i) : (64 + ty * 4 + (i - 4));
            red[rloc][tx] = bb;
        }
        __syncthreads();
        if (t < 128) {
            u64 bb = best[t];
            #pragma unroll
            for (int x = 0; x < 16; ++x) {
                u64 v = red[t][x];
                bb = v < bb ? v : bb;
            }
            best[t] = bb;
        }
        __syncthreads();
    }

    if (t < 128) {
        int row = row0 + t;
        if (row < M_TOK) part[(size_t)row * NCHUNK + chunk] = best[t];
    }
}

// ---------------------------------------------------------------------------
// Kernel: combine chunk argmins -> final indices; also zero the loss slot.
__global__ __launch_bounds__(256) void k_argmin(const u64* __restrict__ part,
                                                int* __restrict__ idxp,
                                                float* __restrict__ loss_slot)
{
    int m = blockIdx.x * 256 + threadIdx.x;
    if (m == 0) *loss_slot = 0.0f;
    if (m < M_TOK) {
        u64 b = ~0ull;
        #pragma unroll
        for (int c = 0; c < NCHUNK; ++c) {
            u64 v = part[(size_t)m * NCHUNK + c];
            b = v < b ? v : b;
        }
        idxp[m] = (int)(u32)(b & 0xffffffffull);
    }
}

// ---------------------------------------------------------------------------
// Kernel: loss = 3 * mean((emb[idx[m]] - zc)^2)
__global__ __launch_bounds__(256) void k_loss(const float* __restrict__ zc,
                                              const float* __restrict__ emb,
                                              const int* __restrict__ idxp,
                                              float* __restrict__ loss_slot)
{
    const size_t total = (size_t)M_TOK * CD;
    float s = 0.0f;
    for (size_t i = (size_t)blockIdx.x * 256 + threadIdx.x; i < total;
         i += (size_t)gridDim.x * 256) {
        int m = (int)(i >> 8);
        int c = (int)(i & 255);
        float e  = emb[(size_t)idxp[m] * CD + c];
        float dz = e - zc[i];
        s += dz * dz;
    }
    #pragma unroll
    for (int o = 32; o; o >>= 1) s += __shfl_down(s, o, 64);
    __shared__ float wsum[4];
    if ((threadIdx.x & 63) == 0) wsum[threadIdx.x >> 6] = s;
    __syncthreads();
    if (threadIdx.x == 0) {
        float tot = wsum[0] + wsum[1] + wsum[2] + wsum[3];
        atomicAdd(loss_slot, tot * (3.0f / (float)((size_t)M_TOK * CD)));
    }
}

// ---------------------------------------------------------------------------
// Kernel: expand GEMM with gather  out[M,768] = emb[idx] @ We[256,768] + be
// 64x64 tile, BK=16, 256 threads, 4x4 micro-tile
__global__ __launch_bounds__(256) void k_expand(const float* __restrict__ emb,
                                                const int* __restrict__ idxp,
                                                const float* __restrict__ W,
                                                const float* __restrict__ bias,
                                                float* __restrict__ out)
{
    __shared__ __align__(16) float As[BK1][64 + 4];
    __shared__ __align__(16) float Bs[BK1][64 + 4];
    __shared__ int rowidx[64];

    const int t  = threadIdx.x;
    const int tx = t & 15, ty = t >> 4;
    const int row0 = blockIdx.x * 64;   // 197
    const int col0 = blockIdx.y * 64;   // 12

    if (t < 64) rowidx[t] = idxp[row0 + t];
    __syncthreads();

    const int la_r = t >> 2;
    const int la_k = (t & 3) << 2;
    const int lb_k = t >> 4;
    const int lb_n = (t & 15) << 2;

    float acc[4][4] = {};

    for (int k0 = 0; k0 < CD; k0 += BK1) {
        float4 a4 = *(const float4*)&emb[(size_t)rowidx[la_r] * CD + k0 + la_k];
        float4 b4 = *(const float4*)&W[(size_t)(k0 + lb_k) * CIN + col0 + lb_n];
        __syncthreads();
        As[la_k + 0][la_r] = a4.x; As[la_k + 1][la_r] = a4.y;
        As[la_k + 2][la_r] = a4.z; As[la_k + 3][la_r] = a4.w;
        *(float4*)&Bs[lb_k][lb_n] = b4;
        __syncthreads();
        #pragma unroll
        for (int k = 0; k < BK1; ++k) {
            float a[4], b[4];
            *(float4*)&a[0] = *(const float4*)&As[k][ty * 4];
            *(float4*)&b[0] = *(const float4*)&Bs[k][tx * 4];
            #pragma unroll
            for (int i = 0; i < 4; ++i)
                #pragma unroll
                for (int j = 0; j < 4; ++j)
                    acc[i][j] = fmaf(a[i], b[j], acc[i][j]);
        }
    }

    float4 bb = *(const float4*)&bias[col0 + tx * 4];
    #pragma unroll
    for (int i = 0; i < 4; ++i) {
        float4 v;
        v.x = acc[i][0] + bb.x; v.y = acc[i][1] + bb.y;
        v.z = acc[i][2] + bb.z; v.w = acc[i][3] + bb.w;
        *(float4*)&out[(size_t)(row0 + ty * 4 + i) * CIN + col0 + tx * 4] = v;
    }
}

// ---------------------------------------------------------------------------
extern "C" void kernel_launch(void* const* d_in, const int* in_sizes, int n_in,
                              void* d_out, int out_size, void* d_ws, size_t ws_size,
                              hipStream_t stream)
{
    (void)in_sizes; (void)n_in; (void)out_size;

    const float* z   = (const float*)d_in[0];
    const float* emb = (const float*)d_in[1];
    const float* Wc  = (const float*)d_in[2];
    const float* bc  = (const float*)d_in[3];
    const float* We  = (const float*)d_in[4];
    const float* be  = (const float*)d_in[5];

    float* out       = (float*)d_out;
    float* loss_slot = out + (size_t)M_TOK * CIN;

    // Workspace layout: enorm | part | idx | (zc if it fits, else alias d_out)
    char* base = (char*)d_ws;
    float* enorm = (float*)base;
    u64*   part  = (u64*)(base + (size_t)NE * 4);                 // 32 KiB offset, 8B-aligned
    int*   idxp  = (int*)(part + (size_t)M_TOK * NCHUNK);
    char*  after = (char*)(idxp + M_TOK);
    size_t small_bytes = (size_t)(after - base);
    size_t zc_bytes    = (size_t)M_TOK * CD * sizeof(float);

    float* zc;
    if (ws_size >= small_bytes + zc_bytes) {
        zc = (float*)after;          // after is 16B-aligned (890112 % 16 == 0)
    } else {
        zc = out;                    // scratch inside output buffer; fully
                                     // overwritten by k_expand afterwards
    }

    k_enorm  <<<NE / 4, 256, 0, stream>>>(emb, enorm);
    k_compress<<<dim3(M_TOK / 64, CD / 64), 256, 0, stream>>>(z, Wc, bc, zc);
    k_dist   <<<dim3((M_TOK + 127) / 128, NCHUNK), 256, 0, stream>>>(zc, emb, enorm, part);
    k_argmin <<<(M_TOK + 255) / 256, 256, 0, stream>>>(part, idxp, loss_slot);
    k_loss   <<<256, 256, 0, stream>>>(zc, emb, idxp, loss_slot);
    k_expand <<<dim3(M_TOK / 64, CIN / 64), 256, 0, stream>>>(emb, idxp, We, be, out);
}

// Round 2
// 383.197 us; speedup vs baseline: 2.6720x; 2.6720x over previous
//
#include <hip/hip_runtime.h>
#include <stdint.h>

// Problem constants (B=64, N=197)
#define M_TOK 12608      // 64*197 tokens
#define MPAD  12672      // 99 * 128 (m-tiles for the coarse dist kernel)
#define CIN   768
#define CD    256
#define NE    8192
#define NCHUNK 8         // nE split into 8 chunks of 1024
#define CHUNK  1024

typedef unsigned long long u64;
typedef unsigned int u32;
typedef _Float16 f16;
typedef _Float16 f16x8 __attribute__((ext_vector_type(8)));
typedef _Float16 f16x4 __attribute__((ext_vector_type(4)));
typedef float f32x4 __attribute__((ext_vector_type(4)));

#if __has_builtin(__builtin_amdgcn_global_load_lds)
#define HAVE_GLL 1
#define GLOAD_LDS(g, l)                                                        \
    __builtin_amdgcn_global_load_lds(                                          \
        (__attribute__((address_space(1))) void*)(g),                          \
        (__attribute__((address_space(3))) void*)(l), 16, 0, 0)
#else
#define HAVE_GLL 0
#endif

// ---------------------------------------------------------------------------
// enorm[j] = sum_k emb[j][k]^2 ; also materialize emb as fp16; zero loss slot.
__global__ __launch_bounds__(256) void k_enorm(const float* __restrict__ emb,
                                               float* __restrict__ enorm,
                                               f16* __restrict__ embf16,
                                               float* __restrict__ loss_slot)
{
    if (blockIdx.x == 0 && threadIdx.x == 0) *loss_slot = 0.0f;
    int row  = blockIdx.x * 4 + (threadIdx.x >> 6);
    int lane = threadIdx.x & 63;
    float4 v = *(const float4*)&emb[(size_t)row * CD + lane * 4];
    f16x4 hv = { (f16)v.x, (f16)v.y, (f16)v.z, (f16)v.w };
    *(f16x4*)&embf16[(size_t)row * CD + lane * 4] = hv;
    float s = v.x*v.x + v.y*v.y + v.z*v.z + v.w*v.w;
    #pragma unroll
    for (int o = 32; o; o >>= 1) s += __shfl_down(s, o, 64);
    if (lane == 0) enorm[row] = s;
}

// ---------------------------------------------------------------------------
// compress GEMM  zc[M,256] = z[M,768] @ Wc[768,256] + bc  (fp32, 64x64 tile)
// Also writes zc in fp16 for the coarse distance kernel.
#define BK1 16
__global__ __launch_bounds__(256) void k_compress(const float* __restrict__ z,
                                                  const float* __restrict__ W,
                                                  const float* __restrict__ bias,
                                                  float* __restrict__ zc,
                                                  f16* __restrict__ zcf16)
{
    __shared__ __align__(16) float As[BK1][64 + 4];
    __shared__ __align__(16) float Bs[BK1][64 + 4];
    const int t  = threadIdx.x;
    const int tx = t & 15, ty = t >> 4;
    const int row0 = blockIdx.x * 64;   // 197 blocks
    const int col0 = blockIdx.y * 64;   // 4 blocks

    const int la_r = t >> 2;
    const int la_k = (t & 3) << 2;
    const int lb_k = t >> 4;
    const int lb_n = (t & 15) << 2;

    float acc[4][4] = {};

    for (int k0 = 0; k0 < CIN; k0 += BK1) {
        float4 a4 = *(const float4*)&z[(size_t)(row0 + la_r) * CIN + k0 + la_k];
        float4 b4 = *(const float4*)&W[(size_t)(k0 + lb_k) * CD + col0 + lb_n];
        __syncthreads();
        As[la_k + 0][la_r] = a4.x; As[la_k + 1][la_r] = a4.y;
        As[la_k + 2][la_r] = a4.z; As[la_k + 3][la_r] = a4.w;
        *(float4*)&Bs[lb_k][lb_n] = b4;
        __syncthreads();
        #pragma unroll
        for (int k = 0; k < BK1; ++k) {
            float a[4], b[4];
            *(float4*)&a[0] = *(const float4*)&As[k][ty * 4];
            *(float4*)&b[0] = *(const float4*)&Bs[k][tx * 4];
            #pragma unroll
            for (int i = 0; i < 4; ++i)
                #pragma unroll
                for (int j = 0; j < 4; ++j)
                    acc[i][j] = fmaf(a[i], b[j], acc[i][j]);
        }
    }

    float4 bb = *(const float4*)&bias[col0 + tx * 4];
    #pragma unroll
    for (int i = 0; i < 4; ++i) {
        float4 v;
        v.x = acc[i][0] + bb.x; v.y = acc[i][1] + bb.y;
        v.z = acc[i][2] + bb.z; v.w = acc[i][3] + bb.w;
        size_t off = (size_t)(row0 + ty * 4 + i) * CD + col0 + tx * 4;
        *(float4*)&zc[off] = v;
        f16x4 hv = { (f16)v.x, (f16)v.y, (f16)v.z, (f16)v.w };
        *(f16x4*)&zcf16[off] = hv;
    }
}

// ---------------------------------------------------------------------------
// Coarse distance GEMM (fp16 MFMA) + per-(row,chunk) approx top-2.
// C[m,j] = dot(zc_m, e_j); d = enorm[j] - 2C. Block: 128 rows x 1024-chunk,
// looped over 8 col-tiles of 128. 4 waves; wave-tile 64x64 = 4x4 of 16x16x32.
// Per-lane running argmin per row-slot (16 slots/lane), cross-lane top-2 at end.
__global__ __launch_bounds__(256) void k_dist_mfma(const f16* __restrict__ zcf16,
                                                   const f16* __restrict__ embf16,
                                                   const float* __restrict__ enorm,
                                                   u64* __restrict__ part)
{
    __shared__ __align__(16) f16 As[128][32];   // 8 KB
    __shared__ __align__(16) f16 Bs[128][32];   // 8 KB
    __shared__ u64 wred[128][2][2];             // 4 KB

    const int t = threadIdx.x;
    const int w = t >> 6;          // wave 0..3
    const int l = t & 63;
    const int wrow = (w >> 1) * 64;
    const int wcol = (w & 1) * 64;
    const int m0    = blockIdx.x * 128;   // 99 blocks
    const int chunk = blockIdx.y;         // 0..7

    // staging lane mapping: inst i covers rows i*64 + w*16 .. +15
    const int st_r = (l >> 2);            // row within 16-group
    const int st_k = (l & 3) * 8;         // f16 elements within 32-wide k

    float bd[16];
    int   bc[16];
    #pragma unroll
    for (int s = 0; s < 16; ++s) { bd[s] = __builtin_inff(); bc[s] = 0; }

    for (int tile = 0; tile < 8; ++tile) {
        const int j0 = chunk * CHUNK + tile * 128;
        f32x4 acc[4][4];
        #pragma unroll
        for (int a = 0; a < 4; ++a)
            #pragma unroll
            for (int b = 0; b < 4; ++b)
                acc[a][b] = (f32x4){0.f, 0.f, 0.f, 0.f};

        for (int ks = 0; ks < 8; ++ks) {        // K = 256, BK = 32
            const int kofs = ks * 32 + st_k;
#if HAVE_GLL
            __syncthreads();   // prior compute done before LDS overwrite
            #pragma unroll
            for (int i = 0; i < 2; ++i) {
                int rr = i * 64 + w * 16;
                const f16* gA = zcf16  + (size_t)(m0 + rr + st_r) * CD + kofs;
                const f16* gB = embf16 + (size_t)(j0 + rr + st_r) * CD + kofs;
                GLOAD_LDS(gA, &As[rr][0]);
                GLOAD_LDS(gB, &Bs[rr][0]);
            }
            __syncthreads();   // compiler drains vmcnt before barrier
#else
            f16x8 va[2], vb[2];
            #pragma unroll
            for (int i = 0; i < 2; ++i) {
                int rr = i * 64 + w * 16;
                va[i] = *(const f16x8*)(zcf16  + (size_t)(m0 + rr + st_r) * CD + kofs);
                vb[i] = *(const f16x8*)(embf16 + (size_t)(j0 + rr + st_r) * CD + kofs);
            }
            __syncthreads();
            #pragma unroll
            for (int i = 0; i < 2; ++i) {
                int rr = i * 64 + w * 16;
                *(f16x8*)&As[rr + st_r][st_k] = va[i];
                *(f16x8*)&Bs[rr + st_r][st_k] = vb[i];
            }
            __syncthreads();
#endif
            f16x8 af[4], bf[4];
            #pragma unroll
            for (int tm = 0; tm < 4; ++tm)
                af[tm] = *(const f16x8*)&As[wrow + tm * 16 + (l & 15)][(l >> 4) * 8];
            #pragma unroll
            for (int tn = 0; tn < 4; ++tn)
                bf[tn] = *(const f16x8*)&Bs[wcol + tn * 16 + (l & 15)][(l >> 4) * 8];
            #pragma unroll
            for (int tm = 0; tm < 4; ++tm)
                #pragma unroll
                for (int tn = 0; tn < 4; ++tn)
                    acc[tm][tn] = __builtin_amdgcn_mfma_f32_16x16x32_f16(
                        af[tm], bf[tn], acc[tm][tn], 0, 0, 0);
        }

        // epilogue: distances + per-lane running argmin per slot
        const int cb = j0 + wcol + (l & 15);
        float en0 = enorm[cb], en1 = enorm[cb + 16], en2 = enorm[cb + 32], en3 = enorm[cb + 48];
        #pragma unroll
        for (int tm = 0; tm < 4; ++tm) {
            #pragma unroll
            for (int reg = 0; reg < 4; ++reg) {
                const int s = tm * 4 + reg;
                float d0 = fmaf(acc[tm][0][reg], -2.f, en0);
                float d1 = fmaf(acc[tm][1][reg], -2.f, en1);
                float d2 = fmaf(acc[tm][2][reg], -2.f, en2);
                float d3 = fmaf(acc[tm][3][reg], -2.f, en3);
                float da = d1 < d0 ? d1 : d0;  int ca = d1 < d0 ? cb + 16 : cb;
                float db = d3 < d2 ? d3 : d2;  int cc = d3 < d2 ? cb + 48 : cb + 32;
                float dm = db < da ? db : da;  int cm = db < da ? cc : ca;
                if (dm < bd[s]) { bd[s] = dm; bc[s] = cm; }
            }
        }
    }

    // pack keys, top-2 across the 16 lanes sharing each row, merge in LDS
    #pragma unroll
    for (int tm = 0; tm < 4; ++tm) {
        #pragma unroll
        for (int reg = 0; reg < 4; ++reg) {
            const int s = tm * 4 + reg;
            u32 u = __float_as_uint(bd[s]);
            u = (u & 0x80000000u) ? ~u : (u | 0x80000000u);
            u64 b  = ((u64)u << 32) | (u32)bc[s];
            u64 sc = ~0ull;
            #pragma unroll
            for (int off = 1; off <= 8; off <<= 1) {
                u64 ob = __shfl_xor(b, off, 64);
                u64 os = __shfl_xor(sc, off, 64);
                u64 nb = b < ob ? b : ob;
                u64 mx = b < ob ? ob : b;
                sc = sc < os ? sc : os;
                sc = sc < mx ? sc : mx;
                b = nb;
            }
            if ((l & 15) == 0) {
                int row = wrow + tm * 16 + (l >> 4) * 4 + reg;
                wred[row][w & 1][0] = b;
                wred[row][w & 1][1] = sc;
            }
        }
    }
    __syncthreads();
    if (t < 128) {
        u64 b0 = wred[t][0][0], s0 = wred[t][0][1];
        u64 b1 = wred[t][1][0], s1 = wred[t][1][1];
        u64 B  = b0 < b1 ? b0 : b1;
        u64 mx = b0 < b1 ? b1 : b0;
        u64 S  = s0 < s1 ? s0 : s1;
        S = S < mx ? S : mx;
        int row = m0 + t;
        if (row < M_TOK) {
            part[((size_t)row * NCHUNK + chunk) * 2 + 0] = B;
            part[((size_t)row * NCHUNK + chunk) * 2 + 1] = S;
        }
    }
}

// ---------------------------------------------------------------------------
// Exact fp32 rescore of the 16 candidates per row -> final index.
__global__ __launch_bounds__(256) void k_rescore(const float* __restrict__ zc,
                                                 const float* __restrict__ emb,
                                                 const float* __restrict__ enorm,
                                                 const u64* __restrict__ part,
                                                 int* __restrict__ idxp)
{
    int row = blockIdx.x * 4 + (threadIdx.x >> 6);
    int l   = threadIdx.x & 63;
    if (row >= M_TOK) return;
    float4 zr = *(const float4*)&zc[(size_t)row * CD + l * 4];
    u64 best = ~0ull;
    for (int c = 0; c < 16; ++c) {
        u64 key = part[(size_t)row * 16 + c];
        int col = (int)((u32)key & (NE - 1));
        float4 er = *(const float4*)&emb[(size_t)col * CD + l * 4];
        float p = zr.x*er.x + zr.y*er.y + zr.z*er.z + zr.w*er.w;
        #pragma unroll
        for (int o = 32; o; o >>= 1) p += __shfl_xor(p, o, 64);
        float d = fmaf(p, -2.f, enorm[col]);
        u32 u = __float_as_uint(d);
        u = (u & 0x80000000u) ? ~u : (u | 0x80000000u);
        u64 k2 = ((u64)u << 32) | (u32)col;
        best = k2 < best ? k2 : best;
    }
    if (l == 0) idxp[row] = (int)((u32)best & (NE - 1));
}

// ---------------------------------------------------------------------------
// loss = 3 * mean((emb[idx[m]] - zc)^2)
__global__ __launch_bounds__(256) void k_loss(const float* __restrict__ zc,
                                              const float* __restrict__ emb,
                                              const int* __restrict__ idxp,
                                              float* __restrict__ loss_slot)
{
    const size_t total = (size_t)M_TOK * CD;
    float s = 0.0f;
    for (size_t i = (size_t)blockIdx.x * 256 + threadIdx.x; i < total;
         i += (size_t)gridDim.x * 256) {
        int m = (int)(i >> 8);
        int c = (int)(i & 255);
        float e  = emb[(size_t)idxp[m] * CD + c];
        float dz = e - zc[i];
        s += dz * dz;
    }
    #pragma unroll
    for (int o = 32; o; o >>= 1) s += __shfl_down(s, o, 64);
    __shared__ float wsum[4];
    if ((threadIdx.x & 63) == 0) wsum[threadIdx.x >> 6] = s;
    __syncthreads();
    if (threadIdx.x == 0) {
        float tot = wsum[0] + wsum[1] + wsum[2] + wsum[3];
        atomicAdd(loss_slot, tot * (3.0f / (float)((size_t)M_TOK * CD)));
    }
}

// ---------------------------------------------------------------------------
// expand GEMM with gather  out[M,768] = emb[idx] @ We[256,768] + be (fp32)
__global__ __launch_bounds__(256) void k_expand(const float* __restrict__ emb,
                                                const int* __restrict__ idxp,
                                                const float* __restrict__ W,
                                                const float* __restrict__ bias,
                                                float* __restrict__ out)
{
    __shared__ __align__(16) float As[BK1][64 + 4];
    __shared__ __align__(16) float Bs[BK1][64 + 4];
    __shared__ int rowidx[64];

    const int t  = threadIdx.x;
    const int tx = t & 15, ty = t >> 4;
    const int row0 = blockIdx.x * 64;   // 197
    const int col0 = blockIdx.y * 64;   // 12

    if (t < 64) rowidx[t] = idxp[row0 + t];
    __syncthreads();

    const int la_r = t >> 2;
    const int la_k = (t & 3) << 2;
    const int lb_k = t >> 4;
    const int lb_n = (t & 15) << 2;

    float acc[4][4] = {};

    for (int k0 = 0; k0 < CD; k0 += BK1) {
        float4 a4 = *(const float4*)&emb[(size_t)rowidx[la_r] * CD + k0 + la_k];
        float4 b4 = *(const float4*)&W[(size_t)(k0 + lb_k) * CIN + col0 + lb_n];
        __syncthreads();
        As[la_k + 0][la_r] = a4.x; As[la_k + 1][la_r] = a4.y;
        As[la_k + 2][la_r] = a4.z; As[la_k + 3][la_r] = a4.w;
        *(float4*)&Bs[lb_k][lb_n] = b4;
        __syncthreads();
        #pragma unroll
        for (int k = 0; k < BK1; ++k) {
            float a[4], b[4];
            *(float4*)&a[0] = *(const float4*)&As[k][ty * 4];
            *(float4*)&b[0] = *(const float4*)&Bs[k][tx * 4];
            #pragma unroll
            for (int i = 0; i < 4; ++i)
                #pragma unroll
                for (int j = 0; j < 4; ++j)
                    acc[i][j] = fmaf(a[i], b[j], acc[i][j]);
        }
    }

    float4 bb = *(const float4*)&bias[col0 + tx * 4];
    #pragma unroll
    for (int i = 0; i < 4; ++i) {
        float4 v;
        v.x = acc[i][0] + bb.x; v.y = acc[i][1] + bb.y;
        v.z = acc[i][2] + bb.z; v.w = acc[i][3] + bb.w;
        *(float4*)&out[(size_t)(row0 + ty * 4 + i) * CIN + col0 + tx * 4] = v;
    }
}

// ---------------------------------------------------------------------------
extern "C" void kernel_launch(void* const* d_in, const int* in_sizes, int n_in,
                              void* d_out, int out_size, void* d_ws, size_t ws_size,
                              hipStream_t stream)
{
    (void)in_sizes; (void)n_in; (void)out_size;

    const float* z   = (const float*)d_in[0];
    const float* emb = (const float*)d_in[1];
    const float* Wc  = (const float*)d_in[2];
    const float* bc  = (const float*)d_in[3];
    const float* We  = (const float*)d_in[4];
    const float* be  = (const float*)d_in[5];

    float* out       = (float*)d_out;
    float* loss_slot = out + (size_t)M_TOK * CIN;

    // Workspace layout (all offsets 256B-aligned):
    //   enorm[NE] f32 | part[M_TOK*16] u64 | idxp[M_TOK] i32 |
    //   embf16[NE*CD] | zcf16[MPAD*CD] | zc[M_TOK*CD] f32 (falls back to d_out)
    char* base = (char*)d_ws;
    size_t off = 0;
    auto align_up = [](size_t x) { return (x + 255) & ~(size_t)255; };

    float* enorm = (float*)(base + off); off = align_up(off + (size_t)NE * 4);
    u64*   part  = (u64*)(base + off);   off = align_up(off + (size_t)M_TOK * 16 * 8);
    int*   idxp  = (int*)(base + off);   off = align_up(off + (size_t)M_TOK * 4);
    f16*   embf16= (f16*)(base + off);   off = align_up(off + (size_t)NE * CD * 2);
    f16*   zcf16 = (f16*)(base + off);   off = align_up(off + (size_t)MPAD * CD * 2);
    size_t zc_bytes = (size_t)M_TOK * CD * sizeof(float);

    float* zc;
    if (ws_size >= off + zc_bytes) {
        zc = (float*)(base + off);
    } else {
        zc = out;   // scratch inside output buffer; fully overwritten by k_expand
    }

    k_enorm   <<<NE / 4, 256, 0, stream>>>(emb, enorm, embf16, loss_slot);
    k_compress<<<dim3(M_TOK / 64, CD / 64), 256, 0, stream>>>(z, Wc, bc, zc, zcf16);
    k_dist_mfma<<<dim3(MPAD / 128, NCHUNK), 256, 0, stream>>>(zcf16, embf16, enorm, part);
    k_rescore <<<(M_TOK + 3) / 4, 256, 0, stream>>>(zc, emb, enorm, part, idxp);
    k_loss    <<<256, 256, 0, stream>>>(zc, emb, idxp, loss_slot);
    k_expand  <<<dim3(M_TOK / 64, CIN / 64), 256, 0, stream>>>(emb, idxp, We, be, out);
}

// Round 3
// 315.892 us; speedup vs baseline: 3.2413x; 1.2131x over previous
//
#include <hip/hip_runtime.h>
#include <stdint.h>

// Problem constants (B=64, N=197)
#define M_TOK 12608      // 64*197 tokens
#define MPAD  12672      // 99 * 128
#define CIN   768
#define CD    256
#define NE    8192
#define NCHUNK 8
#define CHUNK  1024

typedef unsigned long long u64;
typedef unsigned int u32;
typedef _Float16 f16;
typedef _Float16 f16x8 __attribute__((ext_vector_type(8)));
typedef _Float16 f16x4 __attribute__((ext_vector_type(4)));
typedef float f32x4 __attribute__((ext_vector_type(4)));

#if __has_builtin(__builtin_amdgcn_global_load_lds)
#define HAVE_GLL 1
#else
#define HAVE_GLL 0
#endif

// Stage one 16B chunk per lane into LDS. lds_base is wave-uniform; HW (or the
// fallback) adds lane*16.
__device__ __forceinline__ void stage16(const f16* src, char* lds_base, int lane)
{
#if HAVE_GLL
    __builtin_amdgcn_global_load_lds(
        (__attribute__((address_space(1))) void*)(src),
        (__attribute__((address_space(3))) void*)(lds_base), 16, 0, 0);
#else
    *(f16x8*)(lds_base + lane * 16) = *(const f16x8*)src;
#endif
}

// ---------------------------------------------------------------------------
// enorm[j] = sum emb[j]^2 ; emb -> f16 ; zero the loss slot.
__global__ __launch_bounds__(256) void k_enorm(const float* __restrict__ emb,
                                               float* __restrict__ enorm,
                                               f16* __restrict__ embf16,
                                               float* __restrict__ loss_slot)
{
    if (blockIdx.x == 0 && threadIdx.x == 0) *loss_slot = 0.0f;
    int row  = blockIdx.x * 4 + (threadIdx.x >> 6);
    int lane = threadIdx.x & 63;
    float4 v = *(const float4*)&emb[(size_t)row * CD + lane * 4];
    f16x4 hv = { (f16)v.x, (f16)v.y, (f16)v.z, (f16)v.w };
    *(f16x4*)&embf16[(size_t)row * CD + lane * 4] = hv;
    float s = v.x*v.x + v.y*v.y + v.z*v.z + v.w*v.w;
    #pragma unroll
    for (int o = 32; o; o >>= 1) s += __shfl_down(s, o, 64);
    if (lane == 0) enorm[row] = s;
}

// ---------------------------------------------------------------------------
// Weight prep: WcT_hi/lo[n][k] = split(Wc[k][n]) (256x768); WeT[n][k] = (f16)We[k][n] (768x256)
__global__ __launch_bounds__(256) void k_prep_w(const float* __restrict__ Wc,
                                                const float* __restrict__ We,
                                                f16* __restrict__ wchi,
                                                f16* __restrict__ wclo,
                                                f16* __restrict__ wet)
{
    int tid = blockIdx.x * 256 + threadIdx.x;      // < 196608
    {
        int n = tid & 255, k = tid >> 8;
        float v = Wc[(size_t)k * CD + n];
        f16 h = (f16)v;
        wchi[(size_t)n * CIN + k] = h;
        wclo[(size_t)n * CIN + k] = (f16)(v - (float)h);
    }
    {
        int d = tid / CIN, c = tid - d * CIN;
        wet[(size_t)c * CD + d] = (f16)We[(size_t)d * CIN + c];
    }
}

// ---------------------------------------------------------------------------
// z -> z_hi + z_lo (f16 pair, fp32-equivalent)
__global__ __launch_bounds__(256) void k_prep_z(const float* __restrict__ z,
                                                f16* __restrict__ zhi,
                                                f16* __restrict__ zlo)
{
    size_t i4 = (size_t)blockIdx.x * 256 + threadIdx.x;   // float4 idx, 2420736 total
    float4 v = ((const float4*)z)[i4];
    f16x4 h = { (f16)v.x, (f16)v.y, (f16)v.z, (f16)v.w };
    f16x4 lo = { (f16)(v.x - (float)h.x), (f16)(v.y - (float)h.y),
                 (f16)(v.z - (float)h.z), (f16)(v.w - (float)h.w) };
    ((f16x4*)zhi)[i4] = h;
    ((f16x4*)zlo)[i4] = lo;
}

// zc[row][col] = bc[col]  (bias pre-init; GEMM terms atomically accumulate)
__global__ __launch_bounds__(256) void k_init_zc(const float* __restrict__ bc,
                                                 float* __restrict__ zc)
{
    size_t i4 = (size_t)blockIdx.x * 256 + threadIdx.x;   // 806912 total
    ((float4*)zc)[i4] = ((const float4*)bc)[i4 & 63];
}

// zc -> zcf16
__global__ __launch_bounds__(256) void k_zcfin(const float* __restrict__ zc,
                                               f16* __restrict__ zcf16)
{
    size_t i4 = (size_t)blockIdx.x * 256 + threadIdx.x;
    float4 v = ((const float4*)zc)[i4];
    f16x4 h = { (f16)v.x, (f16)v.y, (f16)v.z, (f16)v.w };
    ((f16x4*)zcf16)[i4] = h;
}

// ---------------------------------------------------------------------------
// Split-f16 compress GEMM term: zc += A_term @ B_term^T.
// blockIdx.z: 0 = hi*hi, 1 = hi*lo, 2 = lo*hi. 128x128 tile, BK=64, K=768.
__global__ __launch_bounds__(256) void k_compress3(const f16* __restrict__ zhi,
                                                   const f16* __restrict__ zlo,
                                                   const f16* __restrict__ wchi,
                                                   const f16* __restrict__ wclo,
                                                   float* __restrict__ zc)
{
    __shared__ __align__(16) f16 As[128 * 64];
    __shared__ __align__(16) f16 Bs[128 * 64];

    const int t = threadIdx.x;
    const int w = t >> 6, l = t & 63;
    const int wrow = (w >> 1) * 64, wcol = (w & 1) * 64;
    const int m0   = blockIdx.x * 128;
    const int col0 = blockIdx.y * 128;
    const int term = blockIdx.z;

    const f16* A = (term < 2)  ? zhi  : zlo;
    const f16* B = (term == 1) ? wclo : wchi;

    const int cg   = (t & 7) ^ ((t >> 3) & 7);
    const int rloc = t >> 3;
    const f16* asrc[4]; const f16* bsrc[4];
    #pragma unroll
    for (int i = 0; i < 4; ++i) {
        int r = i * 32 + rloc;
        int am = m0 + r; am = am < M_TOK ? am : (M_TOK - 1);
        asrc[i] = A + (size_t)am * CIN + cg * 8;
        bsrc[i] = B + (size_t)(col0 + r) * CIN + cg * 8;
    }
    const int prd0 = (l >> 4) ^ (l & 7);
    const int prd1 = (4 + (l >> 4)) ^ (l & 7);

    f32x4 acc[4][4];
    #pragma unroll
    for (int a = 0; a < 4; ++a)
        #pragma unroll
        for (int b = 0; b < 4; ++b) acc[a][b] = (f32x4){0.f,0.f,0.f,0.f};

    for (int ks = 0; ks < CIN / 64; ++ks) {
        __syncthreads();
        #pragma unroll
        for (int i = 0; i < 4; ++i) {
            stage16(asrc[i] + ks * 64, (char*)As + (i * 256 + w * 64) * 16, l);
            stage16(bsrc[i] + ks * 64, (char*)Bs + (i * 256 + w * 64) * 16, l);
        }
        __syncthreads();
        #pragma unroll
        for (int kk = 0; kk < 2; ++kk) {
            const int pofs = (kk ? prd1 : prd0) * 16;
            f16x8 af[4], bf[4];
            #pragma unroll
            for (int tm = 0; tm < 4; ++tm)
                af[tm] = *(const f16x8*)((const char*)As + (wrow + tm*16 + (l & 15)) * 128 + pofs);
            #pragma unroll
            for (int tn = 0; tn < 4; ++tn)
                bf[tn] = *(const f16x8*)((const char*)Bs + (wcol + tn*16 + (l & 15)) * 128 + pofs);
            #pragma unroll
            for (int tm = 0; tm < 4; ++tm)
                #pragma unroll
                for (int tn = 0; tn < 4; ++tn)
                    acc[tm][tn] = __builtin_amdgcn_mfma_f32_16x16x32_f16(af[tm], bf[tn], acc[tm][tn], 0, 0, 0);
        }
    }

    #pragma unroll
    for (int tm = 0; tm < 4; ++tm) {
        #pragma unroll
        for (int reg = 0; reg < 4; ++reg) {
            int row = m0 + wrow + tm * 16 + (l >> 4) * 4 + reg;
            if (row < M_TOK) {
                #pragma unroll
                for (int tn = 0; tn < 4; ++tn) {
                    int col = col0 + wcol + tn * 16 + (l & 15);
                    unsafeAtomicAdd(&zc[(size_t)row * CD + col], acc[tm][tn][reg]);
                }
            }
        }
    }
}

// ---------------------------------------------------------------------------
// Coarse distance GEMM (f16 MFMA, BK=64, swizzled LDS) + per-(row,chunk) top-2.
__global__ __launch_bounds__(256) void k_dist_mfma(const f16* __restrict__ zcf16,
                                                   const f16* __restrict__ embf16,
                                                   const float* __restrict__ enorm,
                                                   u64* __restrict__ part)
{
    __shared__ __align__(16) f16 As[128 * 64];
    __shared__ __align__(16) f16 Bs[128 * 64];
    __shared__ u64 wred[128][2][2];

    const int t = threadIdx.x;
    const int w = t >> 6, l = t & 63;
    const int wrow = (w >> 1) * 64, wcol = (w & 1) * 64;
    const int m0    = blockIdx.x * 128;
    const int chunk = blockIdx.y;

    const int cg   = (t & 7) ^ ((t >> 3) & 7);
    const int rloc = t >> 3;
    const f16* asrc[4]; const f16* bsrc[4];
    #pragma unroll
    for (int i = 0; i < 4; ++i) {
        int r = i * 32 + rloc;
        int am = m0 + r; am = am < M_TOK ? am : (M_TOK - 1);
        asrc[i] = zcf16 + (size_t)am * CD + cg * 8;
        bsrc[i] = embf16 + (size_t)r * CD + cg * 8;   // + j0*CD at stage time
    }
    const int prd0 = (l >> 4) ^ (l & 7);
    const int prd1 = (4 + (l >> 4)) ^ (l & 7);

    float bd[16];
    int   bcol[16];
    #pragma unroll
    for (int s = 0; s < 16; ++s) { bd[s] = __builtin_inff(); bcol[s] = 0; }

    for (int tile = 0; tile < 8; ++tile) {
        const int j0 = chunk * CHUNK + tile * 128;
        f32x4 acc[4][4];
        #pragma unroll
        for (int a = 0; a < 4; ++a)
            #pragma unroll
            for (int b = 0; b < 4; ++b) acc[a][b] = (f32x4){0.f,0.f,0.f,0.f};

        for (int ks = 0; ks < 4; ++ks) {        // K = 256
            __syncthreads();
            #pragma unroll
            for (int i = 0; i < 4; ++i) {
                stage16(asrc[i] + ks * 64, (char*)As + (i * 256 + w * 64) * 16, l);
                stage16(bsrc[i] + (size_t)j0 * CD + ks * 64, (char*)Bs + (i * 256 + w * 64) * 16, l);
            }
            __syncthreads();
            #pragma unroll
            for (int kk = 0; kk < 2; ++kk) {
                const int pofs = (kk ? prd1 : prd0) * 16;
                f16x8 af[4], bf[4];
                #pragma unroll
                for (int tm = 0; tm < 4; ++tm)
                    af[tm] = *(const f16x8*)((const char*)As + (wrow + tm*16 + (l & 15)) * 128 + pofs);
                #pragma unroll
                for (int tn = 0; tn < 4; ++tn)
                    bf[tn] = *(const f16x8*)((const char*)Bs + (wcol + tn*16 + (l & 15)) * 128 + pofs);
                #pragma unroll
                for (int tm = 0; tm < 4; ++tm)
                    #pragma unroll
                    for (int tn = 0; tn < 4; ++tn)
                        acc[tm][tn] = __builtin_amdgcn_mfma_f32_16x16x32_f16(af[tm], bf[tn], acc[tm][tn], 0, 0, 0);
            }
        }

        // distances + per-lane running argmin per row-slot
        const int cb = j0 + wcol + (l & 15);
        float en0 = enorm[cb], en1 = enorm[cb + 16], en2 = enorm[cb + 32], en3 = enorm[cb + 48];
        #pragma unroll
        for (int tm = 0; tm < 4; ++tm) {
            #pragma unroll
            for (int reg = 0; reg < 4; ++reg) {
                const int s = tm * 4 + reg;
                float d0 = fmaf(acc[tm][0][reg], -2.f, en0);
                float d1 = fmaf(acc[tm][1][reg], -2.f, en1);
                float d2 = fmaf(acc[tm][2][reg], -2.f, en2);
                float d3 = fmaf(acc[tm][3][reg], -2.f, en3);
                float da = d1 < d0 ? d1 : d0;  int ca = d1 < d0 ? cb + 16 : cb;
                float db = d3 < d2 ? d3 : d2;  int cc = d3 < d2 ? cb + 48 : cb + 32;
                float dm = db < da ? db : da;  int cm = db < da ? cc : ca;
                if (dm < bd[s]) { bd[s] = dm; bcol[s] = cm; }
            }
        }
    }

    // pack keys; top-2 across the 16 lanes sharing each row; merge halves in LDS
    #pragma unroll
    for (int tm = 0; tm < 4; ++tm) {
        #pragma unroll
        for (int reg = 0; reg < 4; ++reg) {
            const int s = tm * 4 + reg;
            u32 u = __float_as_uint(bd[s]);
            u = (u & 0x80000000u) ? ~u : (u | 0x80000000u);
            u64 b  = ((u64)u << 32) | (u32)bcol[s];
            u64 sc = ~0ull;
            #pragma unroll
            for (int off = 1; off <= 8; off <<= 1) {
                u64 ob = __shfl_xor(b, off, 64);
                u64 os = __shfl_xor(sc, off, 64);
                u64 nb = b < ob ? b : ob;
                u64 mx = b < ob ? ob : b;
                sc = sc < os ? sc : os;
                sc = sc < mx ? sc : mx;
                b = nb;
            }
            if ((l & 15) == 0) {
                int row = wrow + tm * 16 + (l >> 4) * 4 + reg;
                wred[row][w & 1][0] = b;
                wred[row][w & 1][1] = sc;
            }
        }
    }
    __syncthreads();
    if (t < 128) {
        u64 b0 = wred[t][0][0], s0 = wred[t][0][1];
        u64 b1 = wred[t][1][0], s1 = wred[t][1][1];
        u64 B  = b0 < b1 ? b0 : b1;
        u64 mx = b0 < b1 ? b1 : b0;
        u64 S  = s0 < s1 ? s0 : s1;
        S = S < mx ? S : mx;
        int row = m0 + t;
        if (row < M_TOK) {
            part[((size_t)row * NCHUNK + chunk) * 2 + 0] = B;
            part[((size_t)row * NCHUNK + chunk) * 2 + 1] = S;
        }
    }
}

// ---------------------------------------------------------------------------
// Exact fp32 rescore of 16 candidates/row -> final index; fused loss.
__global__ __launch_bounds__(256) void k_rescore(const float* __restrict__ zc,
                                                 const float* __restrict__ emb,
                                                 const float* __restrict__ enorm,
                                                 const u64* __restrict__ part,
                                                 int* __restrict__ idxp,
                                                 float* __restrict__ loss_slot)
{
    const int row = blockIdx.x * 4 + (threadIdx.x >> 6);   // grid 3152 -> exactly M_TOK
    const int l   = threadIdx.x & 63;
    __shared__ float lsum[4];

    float4 zr = *(const float4*)&zc[(size_t)row * CD + l * 4];
    u64 best = ~0ull;
    for (int c = 0; c < 16; ++c) {
        u64 key = part[(size_t)row * 16 + c];
        int col = (int)((u32)key & (NE - 1));
        float4 er = *(const float4*)&emb[(size_t)col * CD + l * 4];
        float p = zr.x*er.x + zr.y*er.y + zr.z*er.z + zr.w*er.w;
        #pragma unroll
        for (int o = 32; o; o >>= 1) p += __shfl_xor(p, o, 64);
        float d = fmaf(p, -2.f, enorm[col]);
        u32 u = __float_as_uint(d);
        u = (u & 0x80000000u) ? ~u : (u | 0x80000000u);
        u64 k2 = ((u64)u << 32) | (u32)col;
        best = k2 < best ? k2 : best;
    }
    float zn = zr.x*zr.x + zr.y*zr.y + zr.z*zr.z + zr.w*zr.w;
    #pragma unroll
    for (int o = 32; o; o >>= 1) zn += __shfl_xor(zn, o, 64);

    u32 hi = (u32)(best >> 32);
    float dbest = (hi & 0x80000000u) ? __uint_as_float(hi & 0x7fffffffu)
                                     : __uint_as_float(~hi);
    if (l == 0) {
        idxp[row] = (int)((u32)best & (NE - 1));
        lsum[threadIdx.x >> 6] = dbest + zn;
    }
    __syncthreads();
    if (threadIdx.x == 0) {
        float tot = lsum[0] + lsum[1] + lsum[2] + lsum[3];
        atomicAdd(loss_slot, tot * (3.0f / 3227648.0f));
    }
}

// ---------------------------------------------------------------------------
// Expand GEMM (f16 MFMA, gathered A): out = embf16[idx] @ WeT^T + be. 128x128, K=256.
__global__ __launch_bounds__(256) void k_expand_mfma(const f16* __restrict__ embf16,
                                                     const int* __restrict__ idxp,
                                                     const f16* __restrict__ wet,
                                                     const float* __restrict__ be,
                                                     float* __restrict__ out)
{
    __shared__ __align__(16) f16 As[128 * 64];
    __shared__ __align__(16) f16 Bs[128 * 64];

    const int t = threadIdx.x;
    const int w = t >> 6, l = t & 63;
    const int wrow = (w >> 1) * 64, wcol = (w & 1) * 64;
    const int m0   = blockIdx.x * 128;
    const int col0 = blockIdx.y * 128;

    const int cg   = (t & 7) ^ ((t >> 3) & 7);
    const int rloc = t >> 3;
    const f16* asrc[4]; const f16* bsrc[4];
    #pragma unroll
    for (int i = 0; i < 4; ++i) {
        int r = i * 32 + rloc;
        int m = m0 + r; m = m < M_TOK ? m : (M_TOK - 1);
        int er = idxp[m];
        asrc[i] = embf16 + (size_t)er * CD + cg * 8;
        bsrc[i] = wet + (size_t)(col0 + r) * CD + cg * 8;
    }
    const int prd0 = (l >> 4) ^ (l & 7);
    const int prd1 = (4 + (l >> 4)) ^ (l & 7);

    f32x4 acc[4][4];
    #pragma unroll
    for (int a = 0; a < 4; ++a)
        #pragma unroll
        for (int b = 0; b < 4; ++b) acc[a][b] = (f32x4){0.f,0.f,0.f,0.f};

    for (int ks = 0; ks < 4; ++ks) {            // K = 256
        __syncthreads();
        #pragma unroll
        for (int i = 0; i < 4; ++i) {
            stage16(asrc[i] + ks * 64, (char*)As + (i * 256 + w * 64) * 16, l);
            stage16(bsrc[i] + ks * 64, (char*)Bs + (i * 256 + w * 64) * 16, l);
        }
        __syncthreads();
        #pragma unroll
        for (int kk = 0; kk < 2; ++kk) {
            const int pofs = (kk ? prd1 : prd0) * 16;
            f16x8 af[4], bf[4];
            #pragma unroll
            for (int tm = 0; tm < 4; ++tm)
                af[tm] = *(const f16x8*)((const char*)As + (wrow + tm*16 + (l & 15)) * 128 + pofs);
            #pragma unroll
            for (int tn = 0; tn < 4; ++tn)
                bf[tn] = *(const f16x8*)((const char*)Bs + (wcol + tn*16 + (l & 15)) * 128 + pofs);
            #pragma unroll
            for (int tm = 0; tm < 4; ++tm)
                #pragma unroll
                for (int tn = 0; tn < 4; ++tn)
                    acc[tm][tn] = __builtin_amdgcn_mfma_f32_16x16x32_f16(af[tm], bf[tn], acc[tm][tn], 0, 0, 0);
        }
    }

    float bev[4];
    #pragma unroll
    for (int tn = 0; tn < 4; ++tn) bev[tn] = be[col0 + wcol + tn * 16 + (l & 15)];
    #pragma unroll
    for (int tm = 0; tm < 4; ++tm) {
        #pragma unroll
        for (int reg = 0; reg < 4; ++reg) {
            int row = m0 + wrow + tm * 16 + (l >> 4) * 4 + reg;
            if (row < M_TOK) {
                #pragma unroll
                for (int tn = 0; tn < 4; ++tn) {
                    int col = col0 + wcol + tn * 16 + (l & 15);
                    out[(size_t)row * CIN + col] = acc[tm][tn][reg] + bev[tn];
                }
            }
        }
    }
}

// ---------------------------------------------------------------------------
// fp32 fallback compress (used only if workspace too small for the split path)
#define BK1 16
__global__ __launch_bounds__(256) void k_compress(const float* __restrict__ z,
                                                  const float* __restrict__ W,
                                                  const float* __restrict__ bias,
                                                  float* __restrict__ zc,
                                                  f16* __restrict__ zcf16)
{
    __shared__ __align__(16) float As[BK1][64 + 4];
    __shared__ __align__(16) float Bs[BK1][64 + 4];
    const int t  = threadIdx.x;
    const int tx = t & 15, ty = t >> 4;
    const int row0 = blockIdx.x * 64;
    const int col0 = blockIdx.y * 64;

    const int la_r = t >> 2;
    const int la_k = (t & 3) << 2;
    const int lb_k = t >> 4;
    const int lb_n = (t & 15) << 2;

    float acc[4][4] = {};

    for (int k0 = 0; k0 < CIN; k0 += BK1) {
        float4 a4 = *(const float4*)&z[(size_t)(row0 + la_r) * CIN + k0 + la_k];
        float4 b4 = *(const float4*)&W[(size_t)(k0 + lb_k) * CD + col0 + lb_n];
        __syncthreads();
        As[la_k + 0][la_r] = a4.x; As[la_k + 1][la_r] = a4.y;
        As[la_k + 2][la_r] = a4.z; As[la_k + 3][la_r] = a4.w;
        *(float4*)&Bs[lb_k][lb_n] = b4;
        __syncthreads();
        #pragma unroll
        for (int k = 0; k < BK1; ++k) {
            float a[4], b[4];
            *(float4*)&a[0] = *(const float4*)&As[k][ty * 4];
            *(float4*)&b[0] = *(const float4*)&Bs[k][tx * 4];
            #pragma unroll
            for (int i = 0; i < 4; ++i)
                #pragma unroll
                for (int j = 0; j < 4; ++j)
                    acc[i][j] = fmaf(a[i], b[j], acc[i][j]);
        }
    }

    float4 bb = *(const float4*)&bias[col0 + tx * 4];
    #pragma unroll
    for (int i = 0; i < 4; ++i) {
        float4 v;
        v.x = acc[i][0] + bb.x; v.y = acc[i][1] + bb.y;
        v.z = acc[i][2] + bb.z; v.w = acc[i][3] + bb.w;
        size_t off = (size_t)(row0 + ty * 4 + i) * CD + col0 + tx * 4;
        *(float4*)&zc[off] = v;
        f16x4 hv = { (f16)v.x, (f16)v.y, (f16)v.z, (f16)v.w };
        *(f16x4*)&zcf16[off] = hv;
    }
}

// ---------------------------------------------------------------------------
extern "C" void kernel_launch(void* const* d_in, const int* in_sizes, int n_in,
                              void* d_out, int out_size, void* d_ws, size_t ws_size,
                              hipStream_t stream)
{
    (void)in_sizes; (void)n_in; (void)out_size;

    const float* z   = (const float*)d_in[0];
    const float* emb = (const float*)d_in[1];
    const float* Wc  = (const float*)d_in[2];
    const float* bc  = (const float*)d_in[3];
    const float* We  = (const float*)d_in[4];
    const float* be  = (const float*)d_in[5];

    float* out       = (float*)d_out;
    float* loss_slot = out + (size_t)M_TOK * CIN;

    char* base = (char*)d_ws;
    size_t off = 0;
    auto align_up = [](size_t x) { return (x + 255) & ~(size_t)255; };

    float* enorm = (float*)(base + off); off = align_up(off + (size_t)NE * 4);
    u64*   part  = (u64*)(base + off);   off = align_up(off + (size_t)M_TOK * 16 * 8);
    int*   idxp  = (int*)(base + off);   off = align_up(off + (size_t)M_TOK * 4);
    f16*   embf16= (f16*)(base + off);   off = align_up(off + (size_t)NE * CD * 2);
    f16*   zcf16 = (f16*)(base + off);   off = align_up(off + (size_t)MPAD * CD * 2);
    f16*   wet   = (f16*)(base + off);   off = align_up(off + (size_t)CIN * CD * 2);
    f16*   wchi  = (f16*)(base + off);   off = align_up(off + (size_t)CD * CIN * 2);
    f16*   wclo  = (f16*)(base + off);   off = align_up(off + (size_t)CD * CIN * 2);

    const size_t zsplit_bytes = (size_t)M_TOK * CIN * 2;
    bool have_split = (ws_size >= off + 2 * zsplit_bytes);
    f16 *zhi = nullptr, *zlo = nullptr;
    if (have_split) {
        zhi = (f16*)(base + off); off = align_up(off + zsplit_bytes);
        zlo = (f16*)(base + off); off = align_up(off + zsplit_bytes);
    }
    const size_t zc_bytes = (size_t)M_TOK * CD * 4;
    float* zc = (ws_size >= off + zc_bytes) ? (float*)(base + off) : out;

    k_enorm <<<NE / 4, 256, 0, stream>>>(emb, enorm, embf16, loss_slot);
    k_prep_w<<<(CIN * CD) / 256, 256, 0, stream>>>(Wc, We, wchi, wclo, wet);

    if (have_split) {
        k_prep_z  <<<((size_t)M_TOK * CIN / 4) / 256, 256, 0, stream>>>(z, zhi, zlo);
        k_init_zc <<<((size_t)M_TOK * CD / 4) / 256, 256, 0, stream>>>(bc, zc);
        k_compress3<<<dim3(MPAD / 128, CD / 128, 3), 256, 0, stream>>>(zhi, zlo, wchi, wclo, zc);
        k_zcfin   <<<((size_t)M_TOK * CD / 4) / 256, 256, 0, stream>>>(zc, zcf16);
    } else {
        k_compress<<<dim3(M_TOK / 64, CD / 64), 256, 0, stream>>>(z, Wc, bc, zc, zcf16);
    }

    k_dist_mfma  <<<dim3(MPAD / 128, NCHUNK), 256, 0, stream>>>(zcf16, embf16, enorm, part);
    k_rescore    <<<M_TOK / 4, 256, 0, stream>>>(zc, emb, enorm, part, idxp, loss_slot);
    k_expand_mfma<<<dim3(MPAD / 128, CIN / 128), 256, 0, stream>>>(embf16, idxp, wet, be, out);
}